// Round 11
// baseline (432.251 us; speedup 1.0000x reference)
//
#include <hip/hip_runtime.h>

#define TSTEPS 48
#define OUT_STEPS 24
#define L2E 1.44269504088896340736f
#define ECLAMP 30.0f

typedef short bf16x8 __attribute__((ext_vector_type(8)));
typedef float f32x4 __attribute__((ext_vector_type(4)));

// RNE bf16 hi + truncated-residual lo (weights; off hot path).
__device__ __forceinline__ void bf_split_rne(float f, short& hi, short& lo) {
    unsigned u = __builtin_bit_cast(unsigned, f);
    unsigned r = u + 0x7FFFu + ((u >> 16) & 1u);
    unsigned short hb = (unsigned short)(r >> 16);
    float hif = __builtin_bit_cast(float, (unsigned)hb << 16);
    float lof = f - hif;
    unsigned short lb = (unsigned short)(__builtin_bit_cast(unsigned, lof) >> 16);
    hi = (short)hb; lo = (short)lb;
}

// Per-tile exp2 pre-scale: gates i,f,o get -log2e; gate g (tiles 4,5) -2*log2e.
__device__ __forceinline__ float tile_scale(int t) {
    return (t == 4 || t == 5) ? (-2.0f * L2E) : (-L2E);
}

// A-fragments of PRE-SCALED permuted U^T (hi/lo split), register-resident.
// Row permutation: row R=16t+rho <-> gate=(t>>1), unit u=(rho>>2)*8+(t&1)*4+(rho&3).
__device__ __forceinline__ void load_Ufrags(const float* __restrict__ Uk,
                                            bf16x8* Ahi, bf16x8* Alo, int LQ, int LC) {
    const int ulo = ((LC >> 2) << 3) + (LC & 3);
#pragma unroll
    for (int t = 0; t < 8; ++t) {
        const float s = tile_scale(t);
        const int col = (t >> 1) * 32 + ulo + (t & 1) * 4;
        bf16x8 ah, al;
#pragma unroll
        for (int j = 0; j < 8; ++j) {
            float w = Uk[(LQ * 8 + j) * 128 + col] * s;
            short hb, lb; bf_split_rne(w, hb, lb);
            ah[j] = hb; al[j] = lb;
        }
        Ahi[t] = ah; Alo[t] = al;
    }
}

// One LSTM step; h enters/exits in MFMA B-frag layout (identity recurrence).
// Wk/b per-lane constants come from LDS (quad-uniform broadcast, conflict-free).
// Two gate-halves: only 4 accumulators live at once.
// If NEED_P: fold h . Wd into pp (pred partial) inside the loop.
// NOTE (R9/R10 post-mortem): this scalar activation form is the verified-
// accurate one (absmax 4.88e-4). The packed f32x2 rewrite failed at 6.3e-3
// twice with an un-localized defect — do not reintroduce without a bisect.
template <bool NEED_P>
__device__ __forceinline__ float lstm_step(float x,
    const bf16x8* Ahi, const bf16x8* Alo,
    const float* __restrict__ wkb_cell,   // &wkb[cell][0][0][0]; idx (t*4+LQ)*8
    bf16x8& h_hi, bf16x8& h_lo, float* cs,
    const float* wdv, int LQ) {
    float pp = 0.0f;
    bf16x8 nhh, nhl;
#pragma unroll
    for (int tl = 0; tl < 2; ++tl) {
        f32x4 acc[4];
#pragma unroll
        for (int g = 0; g < 4; ++g) {
            const int t = 2 * g + tl;
            const float* wb = wkb_cell + (t * 4 + LQ) * 8;
            f32x4 wk = *(const f32x4*)wb;         // ds_read_b128 (broadcast)
            f32x4 bb = *(const f32x4*)(wb + 4);   // ds_read_b128
            f32x4 a;
#pragma unroll
            for (int r = 0; r < 4; ++r) a[r] = __builtin_fmaf(x, wk[r], bb[r]);
            a = __builtin_amdgcn_mfma_f32_16x16x32_bf16(Alo[t], h_hi, a, 0, 0, 0);
            a = __builtin_amdgcn_mfma_f32_16x16x32_bf16(Ahi[t], h_lo, a, 0, 0, 0);
            a = __builtin_amdgcn_mfma_f32_16x16x32_bf16(Ahi[t], h_hi, a, 0, 0, 0);
            acc[g] = a;
        }
#pragma unroll
        for (int r = 0; r < 4; ++r) {
            const int j = tl * 4 + r;
            // z pre-scaled: exp2 gives e^-z (e^-2z for g) directly.
            float ei = __builtin_amdgcn_exp2f(acc[0][r]);
            float ef = __builtin_amdgcn_exp2f(acc[1][r]);
            float eg = __builtin_amdgcn_exp2f(__builtin_fminf(acc[2][r], ECLAMP));
            float eo = __builtin_amdgcn_exp2f(acc[3][r]);
            float di = 1.0f + ei, df = 1.0f + ef, dg = 1.0f + eg, do_ = 1.0f + eo;
            float ngs = __builtin_fmaf(eg, 2.0f * L2E, -2.0f * L2E);  // -2L2E*(1-eg)
            float t1 = di * dg;
            float t2 = cs[j] * t1;
            float num = __builtin_fmaf(ngs, df, t2);
            float cn = num * __builtin_amdgcn_rcpf(df * t1);          // scaled c'
            cs[j] = cn;
            float ec = __builtin_amdgcn_exp2f(__builtin_fminf(cn, ECLAMP)); // e^-2c
            float h = (1.0f - ec) * __builtin_amdgcn_rcpf(do_ * (1.0f + ec)); // o*tanh(c)
            if constexpr (NEED_P) pp = __builtin_fmaf(h, wdv[j], pp);
            unsigned u = __builtin_bit_cast(unsigned, h);
            float hif = __builtin_bit_cast(float, u & 0xFFFF0000u);
            float lof = h - hif;
            nhh[j] = (short)(u >> 16);
            nhl[j] = (short)(__builtin_bit_cast(unsigned, lof) >> 16);
        }
    }
    h_hi = nhh;
    h_lo = nhl;
    return pp;
}

// (256,3): best-known passing configuration (R8: 429 µs, absmax 4.88e-4).
__global__ __launch_bounds__(256, 3) void lstm_feedback_mfma7(
    const float* __restrict__ inputs,  // [B, 48]
    const float* __restrict__ Wk_w, const float* __restrict__ Uk_w, const float* __restrict__ b_w,
    const float* __restrict__ Wk_d, const float* __restrict__ Uk_d, const float* __restrict__ b_d,
    const float* __restrict__ Wd, const float* __restrict__ bd,
    float* __restrict__ out,           // [B, 24]
    int B) {
    const int tid = threadIdx.x;       // 4 independent waves per block
    const int w = tid >> 6;
    const int lane = tid & 63;
    const int LQ = lane >> 4;
    const int LC = lane & 15;          // lane's batch column within its wave
    const int mblk = blockIdx.x * 64;

    __shared__ float xbuf[4][16 * 49];     // stride 49: conflict-free column reads
    __shared__ float predbuf[4][16 * 25];  // stride 25: conflict-free scattered writes
    __shared__ __align__(16) float wkb[2][8][4][8];  // [cell][tile][LQ][wk0..3,b0..3]

    // Stage BOTH cells' pre-scaled Wk/b (quad-uniform data; 1 value pair per thread).
    {
        const int cell = tid >> 7, t = (tid >> 4) & 7, q = (tid >> 2) & 3, r = tid & 3;
        const float* Wks = cell ? Wk_d : Wk_w;
        const float* bvs = cell ? b_d : b_w;
        const float s = tile_scale(t);
        const int colb = (t >> 1) * 32 + q * 8 + (t & 1) * 4 + r;
        wkb[cell][t][q][r]     = Wks[colb] * s;
        wkb[cell][t][q][4 + r] = bvs[colb] * s;
    }

    // Block cooperatively loads its 64x48 input tile (coalesced).
    for (int i = tid; i < 64 * TSTEPS; i += 256) {
        int m = i / TSTEPS, t = i - m * TSTEPS;
        xbuf[m >> 4][(m & 15) * 49 + t] = inputs[(long)mblk * TSTEPS + i];
    }

    bf16x8 Ahi[8], Alo[8];
    load_Ufrags(Uk_w, Ahi, Alo, LQ, LC);

    bf16x8 h_hi = {0, 0, 0, 0, 0, 0, 0, 0};
    bf16x8 h_lo = {0, 0, 0, 0, 0, 0, 0, 0};
    float cs[8] = {0, 0, 0, 0, 0, 0, 0, 0};  // scaled cell state (-2*log2e * c)

    __syncthreads();  // xbuf + wkb visible

    const float* __restrict__ xcol = &xbuf[w][LC * 49];
    const float* __restrict__ wkb_w = &wkb[0][0][0][0];
    const float* __restrict__ wkb_d = &wkb[1][0][0][0];

    // ---- warmup: steps 0..46 (pred not needed) ----
    for (int t = 0; t < TSTEPS - 1; ++t) {
        asm volatile("" ::: "memory");  // keep wkb ds_reads inside the loop
        lstm_step<false>(xcol[t], Ahi, Alo, wkb_w, h_hi, h_lo, cs, nullptr, LQ);
    }

    // Wd/bd loaded only now (keeps warmup register pressure down).
    float wdv[8];
#pragma unroll
    for (int j = 0; j < 8; ++j) wdv[j] = Wd[LQ * 8 + j];
    const float bdv = bd[0];

    // ---- last warmup step, with pred fold ----
    asm volatile("" ::: "memory");
    float p = lstm_step<true>(xcol[TSTEPS - 1], Ahi, Alo, wkb_w, h_hi, h_lo, cs, wdv, LQ);
    p += __shfl_xor(p, 16);
    p += __shfl_xor(p, 32);
    p += bdv;                          // all lanes of column LC hold pred(batch LC)
    if (LQ == 0) predbuf[w][LC * 25 + 0] = p;

    // ---- decode: swap U fragments; wkb for decode already staged ----
    load_Ufrags(Uk_d, Ahi, Alo, LQ, LC);

    for (int s = 1; s < OUT_STEPS; ++s) {
        asm volatile("" ::: "memory");
        p = lstm_step<true>(p, Ahi, Alo, wkb_d, h_hi, h_lo, cs, wdv, LQ);
        p += __shfl_xor(p, 16);
        p += __shfl_xor(p, 32);
        p += bdv;
        if (LQ == 0) predbuf[w][LC * 25 + s] = p;
    }

    // ---- coalesced output flush ----
    __syncthreads();
    for (int i = tid; i < 64 * OUT_STEPS; i += 256) {
        int m = i / OUT_STEPS, s = i - m * OUT_STEPS;
        out[(long)mblk * OUT_STEPS + i] = predbuf[m >> 4][(m & 15) * 25 + s];
    }
}

extern "C" void kernel_launch(void* const* d_in, const int* in_sizes, int n_in,
                              void* d_out, int out_size, void* d_ws, size_t ws_size,
                              hipStream_t stream) {
    const float* inputs = (const float*)d_in[0];
    const float* Wk_w   = (const float*)d_in[1];
    const float* Uk_w   = (const float*)d_in[2];
    const float* b_w    = (const float*)d_in[3];
    const float* Wk_d   = (const float*)d_in[4];
    const float* Uk_d   = (const float*)d_in[5];
    const float* b_d    = (const float*)d_in[6];
    const float* Wd     = (const float*)d_in[7];
    const float* bd     = (const float*)d_in[8];
    float* out = (float*)d_out;

    const int B = in_sizes[0] / TSTEPS;
    const int grid = (B + 63) / 64;   // 64 batch rows per 256-thread block
    lstm_feedback_mfma7<<<grid, 256, 0, stream>>>(
        inputs, Wk_w, Uk_w, b_w, Wk_d, Uk_d, b_d, Wd, bd, out, B);
}

// Round 12
// 426.227 us; speedup vs baseline: 1.0141x; 1.0141x over previous
//
#include <hip/hip_runtime.h>

#define TSTEPS 48
#define OUT_STEPS 24
#define L2E 1.44269504088896340736f
#define ECLAMP 30.0f

typedef short bf16x8 __attribute__((ext_vector_type(8)));
typedef float f32x16 __attribute__((ext_vector_type(16)));
typedef unsigned int u32x4 __attribute__((ext_vector_type(4)));

// RNE bf16 hi + truncated-residual lo (weights; off hot path).
__device__ __forceinline__ void bf_split_rne(float f, short& hi, short& lo) {
    unsigned u = __builtin_bit_cast(unsigned, f);
    unsigned r = u + 0x7FFFu + ((u >> 16) & 1u);
    unsigned short hb = (unsigned short)(r >> 16);
    float hif = __builtin_bit_cast(float, (unsigned)hb << 16);
    float lof = f - hif;
    unsigned short lb = (unsigned short)(__builtin_bit_cast(unsigned, lof) >> 16);
    hi = (short)hb; lo = (short)lb;
}

// Truncation split packed into one dword: low16 = hi-bf16, high16 = lo-bf16.
__device__ __forceinline__ unsigned split_pack(float f) {
    unsigned u = __builtin_bit_cast(unsigned, f);
    float hif = __builtin_bit_cast(float, u & 0xFFFF0000u);
    float lof = f - hif;
    unsigned lo = __builtin_bit_cast(unsigned, lof);
    return (u >> 16) | (lo & 0xFFFF0000u);
}

// Gate pre-scale for exp2: i,f,o -> -log2e; g (gate 2) -> -2*log2e.
__device__ __forceinline__ float gate_scale(int g) {
    return (g == 2) ? (-2.0f * L2E) : (-L2E);
}

// A-fragments of pre-scaled U^T for 32x32x16 tiles, tile = whole gate.
// A[g][c] covers K-half c (in-units pi_B(16c + kpos)). Lane: m = lane&31
// (out-unit within gate), H = lane>>5; elem j: in-unit = 16c+4H+(j&3)+8*(j>>2).
__device__ __forceinline__ void load_Ufrags32(const float* __restrict__ Uk,
                                              bf16x8 Ahi[4][2], bf16x8 Alo[4][2],
                                              int m, int H) {
#pragma unroll
    for (int g = 0; g < 4; ++g) {
        const float s = gate_scale(g);
#pragma unroll
        for (int c = 0; c < 2; ++c) {
            bf16x8 ah, al;
#pragma unroll
            for (int j = 0; j < 8; ++j) {
                const int uin = 16 * c + 4 * H + (j & 3) + 8 * (j >> 2);
                float w = Uk[uin * 128 + g * 32 + m] * s;
                short hb, lb; bf_split_rne(w, hb, lb);
                ah[j] = hb; al[j] = lb;
            }
            Ahi[g][c] = ah; Alo[g][c] = al;
        }
    }
}

// A4 per gate: acc-init operand. Nonzero only on H==0 lanes (k=0..4):
// [wk_hi, wk_hi, wk_lo, b_hi, b_lo, 0,0,0]; pairs with B4 = [x_hi,x_lo,x_hi,1,1].
__device__ __forceinline__ void build_A4(const float* __restrict__ Wk,
                                         const float* __restrict__ bv,
                                         bf16x8 A4[4], int m, int H) {
#pragma unroll
    for (int g = 0; g < 4; ++g) {
        const float s = gate_scale(g);
        short whi, wlo, bhi, blo;
        bf_split_rne(Wk[g * 32 + m] * s, whi, wlo);
        bf_split_rne(bv[g * 32 + m] * s, bhi, blo);
        bf16x8 a = {whi, whi, wlo, bhi, blo, 0, 0, 0};
        u32x4 z4 = {0u, 0u, 0u, 0u};
        A4[g] = (H == 0) ? a : __builtin_bit_cast(bf16x8, z4);
    }
}

// One LSTM step for 32 batch rows. h enters/exits as two K-half B-frags
// (identity repack: B0 = D regs 0..7, B1 = regs 8..15 — derived in R12 notes).
// Activation math VERBATIM from R11's verified scalar form (absmax 4.88e-4).
template <bool NEED_P>
__device__ __forceinline__ float lstm_step32(unsigned xpack,
    const bf16x8 Ahi[4][2], const bf16x8 Alo[4][2], const bf16x8 A4[4],
    bf16x8& B0h, bf16x8& B0l, bf16x8& B1h, bf16x8& B1l,
    float* cs, const float* wdv, int H) {
    // B4 on H==0 lanes: [x_hi, x_lo, x_hi, 1, 1, 0,0,0].
    unsigned w0 = xpack;
    unsigned w1 = (xpack & 0xFFFFu) | 0x3F800000u;
    unsigned w2 = 0x00003F80u;
    if (H != 0) { w0 = 0u; w1 = 0u; w2 = 0u; }
    u32x4 b4u = {w0, w1, w2, 0u};
    const bf16x8 B4 = __builtin_bit_cast(bf16x8, b4u);
    const f32x16 zero16 = {0,0,0,0,0,0,0,0,0,0,0,0,0,0,0,0};

    f32x16 acc[4];
#pragma unroll
    for (int g = 0; g < 4; ++g) {
        f32x16 a = __builtin_amdgcn_mfma_f32_32x32x16_bf16(A4[g], B4, zero16, 0, 0, 0);
        // K-half 0 (in-units pi_B(0..15)), 3-product hi/lo.
        a = __builtin_amdgcn_mfma_f32_32x32x16_bf16(Alo[g][0], B0h, a, 0, 0, 0);
        a = __builtin_amdgcn_mfma_f32_32x32x16_bf16(Ahi[g][0], B0l, a, 0, 0, 0);
        a = __builtin_amdgcn_mfma_f32_32x32x16_bf16(Ahi[g][0], B0h, a, 0, 0, 0);
        // K-half 1.
        a = __builtin_amdgcn_mfma_f32_32x32x16_bf16(Alo[g][1], B1h, a, 0, 0, 0);
        a = __builtin_amdgcn_mfma_f32_32x32x16_bf16(Ahi[g][1], B1l, a, 0, 0, 0);
        a = __builtin_amdgcn_mfma_f32_32x32x16_bf16(Ahi[g][1], B1h, a, 0, 0, 0);
        acc[g] = a;
    }

    float pp = 0.0f;
    bf16x8 n0h, n0l, n1h, n1l;
#pragma unroll
    for (int r = 0; r < 16; ++r) {
        // z pre-scaled: exp2 gives e^-z (e^-2z for gate g) directly.
        float ei = __builtin_amdgcn_exp2f(acc[0][r]);
        float ef = __builtin_amdgcn_exp2f(acc[1][r]);
        float eg = __builtin_amdgcn_exp2f(__builtin_fminf(acc[2][r], ECLAMP));
        float eo = __builtin_amdgcn_exp2f(acc[3][r]);
        float di = 1.0f + ei, df = 1.0f + ef, dg = 1.0f + eg, do_ = 1.0f + eo;
        float ngs = __builtin_fmaf(eg, 2.0f * L2E, -2.0f * L2E);  // -2L2E*(1-eg)
        float t1 = di * dg;
        float t2 = cs[r] * t1;
        float num = __builtin_fmaf(ngs, df, t2);
        float cn = num * __builtin_amdgcn_rcpf(df * t1);          // scaled c'
        cs[r] = cn;
        float ec = __builtin_amdgcn_exp2f(__builtin_fminf(cn, ECLAMP)); // e^-2c
        float h = (1.0f - ec) * __builtin_amdgcn_rcpf(do_ * (1.0f + ec)); // o*tanh(c)
        if constexpr (NEED_P) pp = __builtin_fmaf(h, wdv[r], pp);
        unsigned u = __builtin_bit_cast(unsigned, h);
        float hif = __builtin_bit_cast(float, u & 0xFFFF0000u);
        float lof = h - hif;
        short hb = (short)(u >> 16);
        short lb = (short)(__builtin_bit_cast(unsigned, lof) >> 16);
        if (r < 8) { n0h[r] = hb; n0l[r] = lb; }
        else       { n1h[r - 8] = hb; n1l[r - 8] = lb; }
    }
    B0h = n0h; B0l = n0l; B1h = n1h; B1l = n1l;
    return pp;
}

// (256,2): ~200-240 VGPR demand -> 2 waves/SIMD. Occupancy proven not the
// lever (R8); this round halves per-batch fixed cost via 32-batch waves.
__global__ __launch_bounds__(256, 2) void lstm_feedback_mfma10(
    const float* __restrict__ inputs,  // [B, 48]
    const float* __restrict__ Wk_w, const float* __restrict__ Uk_w, const float* __restrict__ b_w,
    const float* __restrict__ Wk_d, const float* __restrict__ Uk_d, const float* __restrict__ b_d,
    const float* __restrict__ Wd, const float* __restrict__ bd,
    float* __restrict__ out,           // [B, 24]
    int B) {
    const int tid = threadIdx.x;       // 4 waves x 32 batch = 128 batch/block
    const int w = tid >> 6;
    const int lane = tid & 63;
    const int m = lane & 31;           // batch column within wave / out-unit row
    const int H = lane >> 5;
    const int mblk = blockIdx.x * 128;

    __shared__ float xbuf[4][32 * 49];     // stride 49: odd -> conflict-free, H-broadcast
    __shared__ float predbuf[4][32 * 25];

    // Block cooperatively loads its 128x48 input tile (coalesced).
    for (int i = tid; i < 128 * TSTEPS; i += 256) {
        int mb = i / TSTEPS, t = i - mb * TSTEPS;
        xbuf[mb >> 5][(mb & 31) * 49 + t] = inputs[(long)mblk * TSTEPS + i];
    }

    bf16x8 Ahi[4][2], Alo[4][2], A4[4];
    load_Ufrags32(Uk_w, Ahi, Alo, m, H);
    build_A4(Wk_w, b_w, A4, m, H);

    u32x4 z4 = {0u, 0u, 0u, 0u};
    bf16x8 B0h = __builtin_bit_cast(bf16x8, z4), B0l = B0h, B1h = B0h, B1l = B0h;
    float cs[16];
#pragma unroll
    for (int r = 0; r < 16; ++r) cs[r] = 0.0f;

    __syncthreads();  // xbuf visible

    const float* __restrict__ xcol = &xbuf[w][m * 49];

    // ---- warmup: steps 0..46 (pred fold compiled out) ----
    for (int t = 0; t < TSTEPS - 1; ++t) {
        lstm_step32<false>(split_pack(xcol[t]), Ahi, Alo, A4,
                           B0h, B0l, B1h, B1l, cs, nullptr, H);
    }

    // Wd per lane: unit of D reg r is (r&3) + 8*(r>>2) + 4H.
    float wdv[16];
#pragma unroll
    for (int r = 0; r < 16; ++r) wdv[r] = Wd[(r & 3) + 8 * (r >> 2) + 4 * H];
    const float bdv = bd[0];

    // ---- last warmup step with pred fold; single-shuffle reduce ----
    float p = lstm_step32<true>(split_pack(xcol[TSTEPS - 1]), Ahi, Alo, A4,
                                B0h, B0l, B1h, B1l, cs, wdv, H);
    p += __shfl_xor(p, 32);
    p += bdv;                          // both H lanes of batch m hold pred(batch m)
    if (H == 0) predbuf[w][m * 25 + 0] = p;

    // ---- decode weights ----
    load_Ufrags32(Uk_d, Ahi, Alo, m, H);
    build_A4(Wk_d, b_d, A4, m, H);

    for (int s = 1; s < OUT_STEPS; ++s) {
        p = lstm_step32<true>(split_pack(p), Ahi, Alo, A4,
                              B0h, B0l, B1h, B1l, cs, wdv, H);
        p += __shfl_xor(p, 32);
        p += bdv;
        if (H == 0) predbuf[w][m * 25 + s] = p;
    }

    // ---- coalesced output flush ----
    __syncthreads();
    for (int i = tid; i < 128 * OUT_STEPS; i += 256) {
        int mb = i / OUT_STEPS, s = i - mb * OUT_STEPS;
        out[(long)mblk * OUT_STEPS + i] = predbuf[mb >> 5][(mb & 31) * 25 + s];
    }
}

extern "C" void kernel_launch(void* const* d_in, const int* in_sizes, int n_in,
                              void* d_out, int out_size, void* d_ws, size_t ws_size,
                              hipStream_t stream) {
    const float* inputs = (const float*)d_in[0];
    const float* Wk_w   = (const float*)d_in[1];
    const float* Uk_w   = (const float*)d_in[2];
    const float* b_w    = (const float*)d_in[3];
    const float* Wk_d   = (const float*)d_in[4];
    const float* Uk_d   = (const float*)d_in[5];
    const float* b_d    = (const float*)d_in[6];
    const float* Wd     = (const float*)d_in[7];
    const float* bd     = (const float*)d_in[8];
    float* out = (float*)d_out;

    const int B = in_sizes[0] / TSTEPS;
    const int grid = (B + 127) / 128;  // 128 batch rows per 256-thread block
    lstm_feedback_mfma10<<<grid, 256, 0, stream>>>(
        inputs, Wk_w, Uk_w, b_w, Wk_d, Uk_d, b_d, Wd, bd, out, B);
}